// Round 1
// baseline (373.272 us; speedup 1.0000x reference)
//
#include <hip/hip_runtime.h>

#define HID 64
#define BSHIFT 9            // 512 nodes per bucket
#define NPB 512
#define NB2 1024            // 2-way (src-shard) bins per bucket
#define P3TILE 4096         // edges per block-tile in partition
#define HISTB 512           // hist blocks in fused hist+input kernel

typedef unsigned int uint;
typedef unsigned short ushort;
typedef unsigned char uchar;
typedef float f32x4 __attribute__((ext_vector_type(4)));
typedef short bf16x8 __attribute__((ext_vector_type(8)));

__device__ inline ushort f2b(float f) {  // fp32 -> bf16 RNE
    uint u = __float_as_uint(f);
    return (ushort)((u + 0x7fffu + ((u >> 16) & 1u)) >> 16);
}

__device__ inline float b2f(ushort b) { return __uint_as_float((uint)b << 16); }

__device__ inline ushort f2h(float f) {  // fp32 -> fp16 (RTE)
    _Float16 h = (_Float16)f;
    return __builtin_bit_cast(ushort, h);
}

__device__ inline float h2f(ushort u) {
    return (float)__builtin_bit_cast(_Float16, u);
}

// unpack 16 fp8-e4m3 (uint4) and accumulate into a[16] via HW cvt
__device__ inline void accf8(float* a, uint4 hv) {
    auto p0 = __builtin_amdgcn_cvt_pk_f32_fp8(hv.x, false);
    auto p1 = __builtin_amdgcn_cvt_pk_f32_fp8(hv.x, true);
    auto p2 = __builtin_amdgcn_cvt_pk_f32_fp8(hv.y, false);
    auto p3 = __builtin_amdgcn_cvt_pk_f32_fp8(hv.y, true);
    auto p4 = __builtin_amdgcn_cvt_pk_f32_fp8(hv.z, false);
    auto p5 = __builtin_amdgcn_cvt_pk_f32_fp8(hv.z, true);
    auto p6 = __builtin_amdgcn_cvt_pk_f32_fp8(hv.w, false);
    auto p7 = __builtin_amdgcn_cvt_pk_f32_fp8(hv.w, true);
    a[0] += p0[0];  a[1] += p0[1];
    a[2] += p1[0];  a[3] += p1[1];
    a[4] += p2[0];  a[5] += p2[1];
    a[6] += p3[0];  a[7] += p3[1];
    a[8] += p4[0];  a[9] += p4[1];
    a[10] += p5[0]; a[11] += p5[1];
    a[12] += p6[0]; a[13] += p6[1];
    a[14] += p7[0]; a[15] += p7[1];
}

__device__ inline uchar f2fp8(float f) {
    return (uchar)(__builtin_amdgcn_cvt_pk_fp8_f32(f, f, 0, false) & 0xff);
}

// ---------------- fused: bucket histogram + input transform ----------------
// blocks [0, HISTB): histogram of dst into buckets
// blocks [HISTB, HISTB+inb): h0 = relu(x @ W_in^T + b_in) -> bf16 hb + fp8 h8

__global__ __launch_bounds__(256) void hist_input(const int* __restrict__ dst,
                                                  int* __restrict__ bcnt, int e, int nb,
                                                  const float* __restrict__ x,
                                                  const float* __restrict__ W_in,
                                                  const float* __restrict__ b_in,
                                                  ushort* __restrict__ hb,
                                                  uchar* __restrict__ h8, int n,
                                                  int inb) {
    __shared__ float smem[576];
    int t = threadIdx.x;
    int b = blockIdx.x;
    if (b < HISTB) {
        int* lh = (int*)smem;
        lh[t] = 0;
        __syncthreads();
        for (int i = b * 256 + t; i < e; i += HISTB * 256)
            atomicAdd(&lh[dst[i] >> BSHIFT], 1);
        __syncthreads();
        if (t < nb && lh[t]) atomicAdd(&bcnt[t], lh[t]);
        return;
    }
    int ib = b - HISTB;
    float* WlT = smem;          // [8][64]
    float* bl = smem + 512;     // [64]
    for (int i = t; i < 512; i += 256) {
        int j = i >> 3, k = i & 7;
        WlT[k * 64 + j] = W_in[i];
    }
    if (t < 64) bl[t] = b_in[t];
    __syncthreads();
    int total2 = n * 32;
    for (int i = ib * 256 + t; i < total2; i += inb * 256) {
        int v = i >> 5;
        int jp = i & 31;
        int j0 = jp * 2, j1 = jp * 2 + 1;
        const float* xr = x + (size_t)v * 8;
        float s0 = bl[j0], s1 = bl[j1];
#pragma unroll
        for (int k = 0; k < 8; ++k) {
            float xv = xr[k];
            s0 += xv * WlT[k * 64 + j0];
            s1 += xv * WlT[k * 64 + j1];
        }
        float o0 = fmaxf(s0, 0.0f), o1 = fmaxf(s1, 0.0f);
        ((uint*)hb)[i] = (uint)f2b(o0) | ((uint)f2b(o1) << 16);
        int pk = __builtin_amdgcn_cvt_pk_fp8_f32(o0, o1, 0, false);
        *(ushort*)&h8[(size_t)2 * i] = (ushort)(pk & 0xffff);
    }
}

__global__ void bucket_scan(const int* __restrict__ bcnt, int* __restrict__ bbase,
                            int* __restrict__ bcur, int* __restrict__ offsets,
                            int e, int nb, int n) {
    __shared__ int sd[256];
    int t = threadIdx.x;
    int v = (t < nb) ? bcnt[t] : 0;
    sd[t] = v;
    __syncthreads();
    for (int off = 1; off < 256; off <<= 1) {
        int u = (t >= off) ? sd[t - off] : 0;
        __syncthreads();
        sd[t] += u;
        __syncthreads();
    }
    int excl = t ? sd[t - 1] : 0;
    if (t < nb) { bbase[t] = excl; bcur[t] = excl; }
    if (t == nb) bbase[t] = e;
    if (t == 0) offsets[n] = e;
}

// partition edges into bucket-contiguous packed (src<<9 | dst&511) array.
// int4-vectorized loads: thread reads 4x int4 (64B contiguous).
__global__ __launch_bounds__(256) void partition(const int* __restrict__ src,
                                                 const int* __restrict__ dst,
                                                 int* __restrict__ bcur,
                                                 int* __restrict__ pair, int e, int nb) {
    __shared__ int lh[256], cb[256];
    int t = threadIdx.x;
    int base = blockIdx.x * P3TILE;
    lh[t] = 0;
    __syncthreads();
    int s[16], d[16], r[16];
    if (base + P3TILE <= e) {
        const int4* s4 = (const int4*)(src + base);
        const int4* d4 = (const int4*)(dst + base);
#pragma unroll
        for (int k = 0; k < 4; ++k) {
            int4 sv = s4[t * 4 + k];
            int4 dv = d4[t * 4 + k];
            s[k * 4 + 0] = sv.x; s[k * 4 + 1] = sv.y;
            s[k * 4 + 2] = sv.z; s[k * 4 + 3] = sv.w;
            d[k * 4 + 0] = dv.x; d[k * 4 + 1] = dv.y;
            d[k * 4 + 2] = dv.z; d[k * 4 + 3] = dv.w;
        }
#pragma unroll
        for (int k = 0; k < 16; ++k)
            r[k] = atomicAdd(&lh[d[k] >> BSHIFT], 1);
        __syncthreads();
        if (t < nb && lh[t]) cb[t] = atomicAdd(&bcur[t], lh[t]);
        __syncthreads();
#pragma unroll
        for (int k = 0; k < 16; ++k)
            pair[cb[d[k] >> BSHIFT] + r[k]] = (s[k] << BSHIFT) | (d[k] & (NPB - 1));
    } else {
#pragma unroll
        for (int k = 0; k < 16; ++k) {
            int i = base + t * 16 + k;
            if (i < e) {
                s[k] = src[i];
                d[k] = dst[i];
                r[k] = atomicAdd(&lh[d[k] >> BSHIFT], 1);
            }
        }
        __syncthreads();
        if (t < nb && lh[t]) cb[t] = atomicAdd(&bcur[t], lh[t]);
        __syncthreads();
#pragma unroll
        for (int k = 0; k < 16; ++k) {
            int i = base + t * 16 + k;
            if (i < e)
                pair[cb[d[k] >> BSHIFT] + r[k]] = (s[k] << BSHIFT) | (d[k] & (NPB - 1));
        }
    }
}

// 1024 threads/block: 16 waves for latency hiding.
// Per-node 2-way partition by src shard (src < half first, then src >= half),
// so the aggregate can run in two temporally-separated phases whose gather
// working set (3.2MB) fits a single XCD's 4MB L2.
__global__ __launch_bounds__(1024) void build_csr(const int* __restrict__ pair,
                                                  const int* __restrict__ bbase,
                                                  int* __restrict__ offsets,
                                                  int* __restrict__ mid,
                                                  float* __restrict__ invdeg,
                                                  int* __restrict__ col, int n,
                                                  int half) {
    __shared__ int bins[NB2], cur[NB2], sd[NB2];
    int b = blockIdx.x, t = threadIdx.x;
    int cbase = bbase[b], cend = bbase[b + 1];
    int v0 = b << BSHIFT;
    bins[t] = 0;
    __syncthreads();
    for (int i = cbase + t; i < cend; i += 1024) {
        int p = pair[i];
        int b2 = ((p & (NPB - 1)) << 1) | ((p >> BSHIFT) >= half);
        atomicAdd(&bins[b2], 1);
    }
    __syncthreads();
    int d = bins[t];
    sd[t] = d;
    __syncthreads();
    for (int off = 1; off < NB2; off <<= 1) {
        int u = (t >= off) ? sd[t - off] : 0;
        __syncthreads();
        sd[t] += u;
        __syncthreads();
    }
    int excl = sd[t] - d;   // exclusive scan
    cur[t] = excl;
    if ((t & 1) == 0) {
        int v = v0 + (t >> 1);
        if (v < n) {
            offsets[v] = cbase + excl;   // start of shard-0 run
            mid[v] = cbase + sd[t];      // start of shard-1 run
            int dtot = d + bins[t + 1];
            invdeg[v] = dtot > 0 ? 1.0f / (float)dtot : 0.0f;
        }
    }
    __syncthreads();
    for (int i = cbase + t; i < cend; i += 1024) {
        int p = pair[i];
        int b2 = ((p & (NPB - 1)) << 1) | ((p >> BSHIFT) >= half);
        int pos = atomicAdd(&cur[b2], 1);
        col[cbase + pos] = p >> BSHIFT;
    }
}

// ---------------- weight prep ----------------

__global__ __launch_bounds__(256) void prep_w(const float* __restrict__ Ws,
                                              const float* __restrict__ Wn,
                                              ushort* __restrict__ Wcat, int total) {
    int i = blockIdx.x * 256 + threadIdx.x;
    if (i >= total) return;
    int l = i >> 13;
    int r = i & 8191;
    int j = r >> 7;
    int k = r & 127;
    float v = (k < 64) ? Ws[l * 4096 + j * 64 + k] : Wn[l * 4096 + j * 64 + (k - 64)];
    Wcat[i] = f2b(v);
}

// ---------------- neighbor mean: quarter-wave/node, fp8 gather (64B rows) ----
// Two phases: PHASE 0 gathers from src rows [0, half) and writes fp16 partial
// sums; PHASE 1 gathers from [half, n), adds the partial, scales by invdeg and
// writes bf16. The dispatch boundary temporally separates the two gather
// working sets so each (3.2MB) stays L2-resident per XCD.

template <int PHASE>
__global__ __launch_bounds__(256) void aggregate_ph(const uchar* __restrict__ h8,
                                                    const int* __restrict__ offsets,
                                                    const int* __restrict__ mid,
                                                    const int* __restrict__ col,
                                                    const float* __restrict__ invdeg,
                                                    ushort* __restrict__ nmP,
                                                    ushort* __restrict__ nmb, int n) {
    int t = threadIdx.x, lane = t & 63, wid = t >> 6;
    int q = lane >> 4;          // quarter -> node
    int fl = lane & 15;         // col staging lane
    int e4 = lane & 3;          // which 16B (16 features) of the 64B row
    int sl = (lane >> 2) & 3;   // edge slot
    int nwaves = gridDim.x * 4;
    int ngrp = (n + 3) >> 2;
    for (int w = blockIdx.x * 4 + wid; w < ngrp; w += nwaves) {
        int v = w * 4 + q;
        bool valid = v < n;
        int vv = valid ? v : n - 1;
        int s0, e0;
        if (PHASE == 0) {
            s0 = offsets[vv];
            e0 = mid[vv];
        } else {
            s0 = mid[vv];
            e0 = offsets[vv + 1];
        }
        int dg = e0 - s0;
        const int* cp = col + s0;
        int deg16 = dg & ~15;
        float acc[16];
        if (PHASE == 0) {
#pragma unroll
            for (int k = 0; k < 16; ++k) acc[k] = 0.f;
        } else {
            // all 4 slots load the same partial and scale by 0.25; the final
            // 4-slot reduce multiplies back by 4 exactly.
            uint4 plo = *(const uint4*)&nmP[(size_t)vv * HID + e4 * 16];
            uint4 phi = *(const uint4*)&nmP[(size_t)vv * HID + e4 * 16 + 8];
            acc[0] = h2f((ushort)(plo.x & 0xffff)) * 0.25f;
            acc[1] = h2f((ushort)(plo.x >> 16)) * 0.25f;
            acc[2] = h2f((ushort)(plo.y & 0xffff)) * 0.25f;
            acc[3] = h2f((ushort)(plo.y >> 16)) * 0.25f;
            acc[4] = h2f((ushort)(plo.z & 0xffff)) * 0.25f;
            acc[5] = h2f((ushort)(plo.z >> 16)) * 0.25f;
            acc[6] = h2f((ushort)(plo.w & 0xffff)) * 0.25f;
            acc[7] = h2f((ushort)(plo.w >> 16)) * 0.25f;
            acc[8] = h2f((ushort)(phi.x & 0xffff)) * 0.25f;
            acc[9] = h2f((ushort)(phi.x >> 16)) * 0.25f;
            acc[10] = h2f((ushort)(phi.y & 0xffff)) * 0.25f;
            acc[11] = h2f((ushort)(phi.y >> 16)) * 0.25f;
            acc[12] = h2f((ushort)(phi.z & 0xffff)) * 0.25f;
            acc[13] = h2f((ushort)(phi.z >> 16)) * 0.25f;
            acc[14] = h2f((ushort)(phi.w & 0xffff)) * 0.25f;
            acc[15] = h2f((ushort)(phi.w >> 16)) * 0.25f;
        }
        // main chunks of 16 edges, with next-chunk col prefetch to break the
        // col-load -> shfl -> gather serial chain
        int idx16 = 0;
        if (deg16 > 0) idx16 = cp[fl];
        for (int base = 0; base < deg16; base += 16) {
            int ci = idx16;
            if (base + 16 < deg16) idx16 = cp[base + 16 + fl];
#pragma unroll
            for (int jj = 0; jj < 16; jj += 4) {
                int ne = __shfl(ci, q * 16 + jj + sl);
                uint4 hv = *(const uint4*)&h8[(size_t)ne * HID + e4 * 16];
                accf8(acc, hv);
            }
        }
        // tail (<16 edges): guarded, no shfl (direct quarter-local col loads)
        for (int jj = 0; jj < 16; jj += 4) {
            if (deg16 + jj >= dg) break;   // uniform within quarter
            int j = deg16 + jj + sl;
            if (j < dg) {
                int ne = cp[j];
                uint4 hv = *(const uint4*)&h8[(size_t)ne * HID + e4 * 16];
                accf8(acc, hv);
            }
        }
        // reduce over the 4 edge slots (lane bits 2-3)
#pragma unroll
        for (int k = 0; k < 16; ++k) {
            acc[k] += __shfl_xor(acc[k], 4);
            acc[k] += __shfl_xor(acc[k], 8);
        }
        if (valid && sl == 0) {
            uint4 lo, hi;
            if (PHASE == 0) {
                lo.x = (uint)f2h(acc[0]) | ((uint)f2h(acc[1]) << 16);
                lo.y = (uint)f2h(acc[2]) | ((uint)f2h(acc[3]) << 16);
                lo.z = (uint)f2h(acc[4]) | ((uint)f2h(acc[5]) << 16);
                lo.w = (uint)f2h(acc[6]) | ((uint)f2h(acc[7]) << 16);
                hi.x = (uint)f2h(acc[8]) | ((uint)f2h(acc[9]) << 16);
                hi.y = (uint)f2h(acc[10]) | ((uint)f2h(acc[11]) << 16);
                hi.z = (uint)f2h(acc[12]) | ((uint)f2h(acc[13]) << 16);
                hi.w = (uint)f2h(acc[14]) | ((uint)f2h(acc[15]) << 16);
                *(uint4*)&nmP[(size_t)v * HID + e4 * 16] = lo;
                *(uint4*)&nmP[(size_t)v * HID + e4 * 16 + 8] = hi;
            } else {
                float s = invdeg[vv];
                lo.x = (uint)f2b(acc[0] * s) | ((uint)f2b(acc[1] * s) << 16);
                lo.y = (uint)f2b(acc[2] * s) | ((uint)f2b(acc[3] * s) << 16);
                lo.z = (uint)f2b(acc[4] * s) | ((uint)f2b(acc[5] * s) << 16);
                lo.w = (uint)f2b(acc[6] * s) | ((uint)f2b(acc[7] * s) << 16);
                hi.x = (uint)f2b(acc[8] * s) | ((uint)f2b(acc[9] * s) << 16);
                hi.y = (uint)f2b(acc[10] * s) | ((uint)f2b(acc[11] * s) << 16);
                hi.z = (uint)f2b(acc[12] * s) | ((uint)f2b(acc[13] * s) << 16);
                hi.w = (uint)f2b(acc[14] * s) | ((uint)f2b(acc[15] * s) << 16);
                *(uint4*)&nmb[(size_t)v * HID + e4 * 16] = lo;
                *(uint4*)&nmb[(size_t)v * HID + e4 * 16 + 8] = hi;
            }
        }
    }
}

// ---------------- per-layer transform via MFMA, bf16 residual ----------------

__global__ __launch_bounds__(256) void transform_mfma(
    const ushort* __restrict__ hbm, const ushort* __restrict__ nmb,
    ushort* __restrict__ hbout, uchar* __restrict__ h8out,
    float* __restrict__ outF, const ushort* __restrict__ Wcat,
    const float* __restrict__ bias, const float* __restrict__ gamma,
    const float* __restrict__ beta, int n, int last) {
    int t = threadIdx.x, lane = t & 63, wid = t >> 6;
    int c = lane & 15, g = lane >> 4;
    bf16x8 Bf[4][4];
#pragma unroll
    for (int tt = 0; tt < 4; ++tt)
#pragma unroll
        for (int s = 0; s < 4; ++s)
            Bf[s][tt] = *(const bf16x8*)&Wcat[(tt * 16 + c) * 128 + s * 32 + g * 8];
    float bcol[4], gcol[4], btc[4];
#pragma unroll
    for (int tt = 0; tt < 4; ++tt) {
        bcol[tt] = bias[tt * 16 + c];
        gcol[tt] = gamma[tt * 16 + c];
        btc[tt] = beta[tt * 16 + c];
    }
    int ntiles = (n + 15) >> 4;
    int nw = gridDim.x * 4;
    for (int tile = blockIdx.x * 4 + wid; tile < ntiles; tile += nw) {
        int m0 = tile << 4;
        int node = m0 + c;
        int nodeL = node < n ? node : n - 1;
        bf16x8 Af[4];
#pragma unroll
        for (int s = 0; s < 2; ++s)
            Af[s] = *(const bf16x8*)&hbm[(size_t)nodeL * HID + s * 32 + g * 8];
#pragma unroll
        for (int s = 0; s < 2; ++s)
            Af[2 + s] = *(const bf16x8*)&nmb[(size_t)nodeL * HID + s * 32 + g * 8];
        f32x4 acc[4] = {{0, 0, 0, 0}, {0, 0, 0, 0}, {0, 0, 0, 0}, {0, 0, 0, 0}};
#pragma unroll
        for (int tt = 0; tt < 4; ++tt)
#pragma unroll
            for (int s = 0; s < 4; ++s)
                acc[tt] = __builtin_amdgcn_mfma_f32_16x16x32_bf16(Af[s], Bf[s][tt],
                                                                 acc[tt], 0, 0, 0);
        float v[4][4];
#pragma unroll
        for (int tt = 0; tt < 4; ++tt)
#pragma unroll
            for (int r = 0; r < 4; ++r) v[tt][r] = acc[tt][r] + bcol[tt];
#pragma unroll
        for (int r = 0; r < 4; ++r) {
            float s = v[0][r] + v[1][r] + v[2][r] + v[3][r];
            s += __shfl_xor(s, 1);
            s += __shfl_xor(s, 2);
            s += __shfl_xor(s, 4);
            s += __shfl_xor(s, 8);
            float mu = s * (1.0f / 64.0f);
            float ss = 0.f;
#pragma unroll
            for (int tt = 0; tt < 4; ++tt) {
                float d = v[tt][r] - mu;
                ss += d * d;
            }
            ss += __shfl_xor(ss, 1);
            ss += __shfl_xor(ss, 2);
            ss += __shfl_xor(ss, 4);
            ss += __shfl_xor(ss, 8);
            float inv = rsqrtf(ss * (1.0f / 64.0f) + 1e-5f);
            int nr = m0 + g * 4 + r;
            if (nr < n) {
#pragma unroll
                for (int tt = 0; tt < 4; ++tt) {
                    int j = tt * 16 + c;
                    float hl = (v[tt][r] - mu) * inv * gcol[tt] + btc[tt];
                    float hv = b2f(hbm[(size_t)nr * HID + j]);
                    float o = hv + fmaxf(hl, 0.0f);
                    if (last) {
                        outF[(size_t)nr * HID + j] = o;   // hb/h8 writes dead
                    } else {
                        hbout[(size_t)nr * HID + j] = f2b(o);
                        h8out[(size_t)nr * HID + j] = f2fp8(o);
                    }
                }
            }
        }
    }
}

// ---------------- launcher ----------------

extern "C" void kernel_launch(void* const* d_in, const int* in_sizes, int n_in,
                              void* d_out, int out_size, void* d_ws, size_t ws_size,
                              hipStream_t stream) {
    const float* x = (const float*)d_in[0];
    const int* edge_src = (const int*)d_in[1];
    const int* edge_dst = (const int*)d_in[2];
    const float* W_in = (const float*)d_in[3];
    const float* b_in = (const float*)d_in[4];
    const float* Ws_self = (const float*)d_in[5];
    const float* Ws_neigh = (const float*)d_in[6];
    const float* biases = (const float*)d_in[7];
    const float* gammas = (const float*)d_in[8];
    const float* betas = (const float*)d_in[9];
    float* out = (float*)d_out;

    int n = in_sizes[0] / 8;
    int e = in_sizes[1];
    int nb = (n + NPB - 1) >> BSHIFT;
    int half = (n + 1) >> 1;   // src shard boundary: rows [0,half) / [half,n)

    char* w = (char*)d_ws;
    size_t off = 0;
    auto carve = [&](size_t bytes) -> void* {
        void* p = w + off;
        off = (off + bytes + 255) & ~(size_t)255;
        return p;
    };
    int* offsets = (int*)carve((size_t)(n + 1) * 4);
    int* mid = (int*)carve((size_t)(n + 1) * 4);
    float* invdeg = (float*)carve((size_t)n * 4);
    int* bcnt = (int*)carve(1024 * 4);
    int* bbase = (int*)carve(1024 * 4);
    int* bcur = (int*)carve(1024 * 4);
    int* col = (int*)carve((size_t)e * 4);
    int* pairbuf = (int*)carve((size_t)e * 4);
    ushort* hb = (ushort*)carve((size_t)n * HID * 2);
    ushort* nm16 = (ushort*)carve((size_t)n * HID * 2);
    uchar* h8 = (uchar*)carve((size_t)n * HID);
    ushort* Wcat = (ushort*)carve(3 * 64 * 128 * 2);
    // fp16 partial-sum buffer: reuse pairbuf (dead after build_csr) when it
    // is large enough (e*4 bytes vs n*HID*2 bytes), else carve fresh.
    size_t needP = (size_t)n * HID * 2;
    ushort* nmP = ((size_t)e * 4 >= needP) ? (ushort*)pairbuf
                                           : (ushort*)carve(needP);
    (void)ws_size;

    hipMemsetAsync(bcnt, 0, 1024 * 4, stream);
    hist_input<<<HISTB + 2048, 256, 0, stream>>>(edge_dst, bcnt, e, nb,
                                                 x, W_in, b_in, hb, h8, n, 2048);
    bucket_scan<<<1, 256, 0, stream>>>(bcnt, bbase, bcur, offsets, e, nb, n);
    partition<<<(e + P3TILE - 1) / P3TILE, 256, 0, stream>>>(edge_src, edge_dst, bcur,
                                                            pairbuf, e, nb);
    build_csr<<<nb, 1024, 0, stream>>>(pairbuf, bbase, offsets, mid, invdeg, col, n,
                                       half);
    prep_w<<<(3 * 8192 + 255) / 256, 256, 0, stream>>>(Ws_self, Ws_neigh, Wcat, 3 * 8192);

    int tfblocks = ((n + 15) / 16 + 3) / 4;
    for (int l = 0; l < 3; ++l) {
        aggregate_ph<0><<<2048, 256, 0, stream>>>(h8, offsets, mid, col, invdeg,
                                                  nmP, nm16, n);
        aggregate_ph<1><<<2048, 256, 0, stream>>>(h8, offsets, mid, col, invdeg,
                                                  nmP, nm16, n);
        transform_mfma<<<tfblocks, 256, 0, stream>>>(hb, nm16, hb, h8, out,
                                                     Wcat + (size_t)l * 8192,
                                                     biases + l * 64, gammas + l * 64,
                                                     betas + l * 64, n, l == 2 ? 1 : 0);
    }
}

// Round 2
// 340.197 us; speedup vs baseline: 1.0972x; 1.0972x over previous
//
#include <hip/hip_runtime.h>

#define HID 64
#define BSHIFT 9            // 512 nodes per bucket
#define NPB 512
#define P3TILE 4096         // edges per block-tile in partition
#define HISTB 512           // hist blocks in fused hist+input kernel

typedef unsigned int uint;
typedef unsigned short ushort;
typedef unsigned char uchar;
typedef float f32x4 __attribute__((ext_vector_type(4)));
typedef short bf16x8 __attribute__((ext_vector_type(8)));

__device__ inline ushort f2b(float f) {  // fp32 -> bf16 RNE
    uint u = __float_as_uint(f);
    return (ushort)((u + 0x7fffu + ((u >> 16) & 1u)) >> 16);
}

__device__ inline float b2f(ushort b) { return __uint_as_float((uint)b << 16); }

// unpack 16 fp8-e4m3 (uint4) and accumulate into a[16] via HW cvt
__device__ inline void accf8(float* a, uint4 hv) {
    auto p0 = __builtin_amdgcn_cvt_pk_f32_fp8(hv.x, false);
    auto p1 = __builtin_amdgcn_cvt_pk_f32_fp8(hv.x, true);
    auto p2 = __builtin_amdgcn_cvt_pk_f32_fp8(hv.y, false);
    auto p3 = __builtin_amdgcn_cvt_pk_f32_fp8(hv.y, true);
    auto p4 = __builtin_amdgcn_cvt_pk_f32_fp8(hv.z, false);
    auto p5 = __builtin_amdgcn_cvt_pk_f32_fp8(hv.z, true);
    auto p6 = __builtin_amdgcn_cvt_pk_f32_fp8(hv.w, false);
    auto p7 = __builtin_amdgcn_cvt_pk_f32_fp8(hv.w, true);
    a[0] += p0[0];  a[1] += p0[1];
    a[2] += p1[0];  a[3] += p1[1];
    a[4] += p2[0];  a[5] += p2[1];
    a[6] += p3[0];  a[7] += p3[1];
    a[8] += p4[0];  a[9] += p4[1];
    a[10] += p5[0]; a[11] += p5[1];
    a[12] += p6[0]; a[13] += p6[1];
    a[14] += p7[0]; a[15] += p7[1];
}

__device__ inline uchar f2fp8(float f) {
    return (uchar)(__builtin_amdgcn_cvt_pk_fp8_f32(f, f, 0, false) & 0xff);
}

// ---------------- fused: bucket histogram + input transform ----------------
// blocks [0, HISTB): histogram of dst into buckets
// blocks [HISTB, HISTB+inb): h0 = relu(x @ W_in^T + b_in) -> bf16 hb + fp8 h8

__global__ __launch_bounds__(256) void hist_input(const int* __restrict__ dst,
                                                  int* __restrict__ bcnt, int e, int nb,
                                                  const float* __restrict__ x,
                                                  const float* __restrict__ W_in,
                                                  const float* __restrict__ b_in,
                                                  ushort* __restrict__ hb,
                                                  uchar* __restrict__ h8, int n,
                                                  int inb) {
    __shared__ float smem[576];
    int t = threadIdx.x;
    int b = blockIdx.x;
    if (b < HISTB) {
        int* lh = (int*)smem;
        lh[t] = 0;
        __syncthreads();
        for (int i = b * 256 + t; i < e; i += HISTB * 256)
            atomicAdd(&lh[dst[i] >> BSHIFT], 1);
        __syncthreads();
        if (t < nb && lh[t]) atomicAdd(&bcnt[t], lh[t]);
        return;
    }
    int ib = b - HISTB;
    float* WlT = smem;          // [8][64]
    float* bl = smem + 512;     // [64]
    for (int i = t; i < 512; i += 256) {
        int j = i >> 3, k = i & 7;
        WlT[k * 64 + j] = W_in[i];
    }
    if (t < 64) bl[t] = b_in[t];
    __syncthreads();
    int total2 = n * 32;
    for (int i = ib * 256 + t; i < total2; i += inb * 256) {
        int v = i >> 5;
        int jp = i & 31;
        int j0 = jp * 2, j1 = jp * 2 + 1;
        const float* xr = x + (size_t)v * 8;
        float s0 = bl[j0], s1 = bl[j1];
#pragma unroll
        for (int k = 0; k < 8; ++k) {
            float xv = xr[k];
            s0 += xv * WlT[k * 64 + j0];
            s1 += xv * WlT[k * 64 + j1];
        }
        float o0 = fmaxf(s0, 0.0f), o1 = fmaxf(s1, 0.0f);
        ((uint*)hb)[i] = (uint)f2b(o0) | ((uint)f2b(o1) << 16);
        int pk = __builtin_amdgcn_cvt_pk_fp8_f32(o0, o1, 0, false);
        *(ushort*)&h8[(size_t)2 * i] = (ushort)(pk & 0xffff);
    }
}

__global__ void bucket_scan(const int* __restrict__ bcnt, int* __restrict__ bbase,
                            int* __restrict__ bcur, int* __restrict__ offsets,
                            int e, int nb, int n) {
    __shared__ int sd[256];
    int t = threadIdx.x;
    int v = (t < nb) ? bcnt[t] : 0;
    sd[t] = v;
    __syncthreads();
    for (int off = 1; off < 256; off <<= 1) {
        int u = (t >= off) ? sd[t - off] : 0;
        __syncthreads();
        sd[t] += u;
        __syncthreads();
    }
    int excl = t ? sd[t - 1] : 0;
    if (t < nb) { bbase[t] = excl; bcur[t] = excl; }
    if (t == nb) bbase[t] = e;
    if (t == 0) offsets[n] = e;
}

// partition edges into bucket-contiguous packed (src<<9 | dst&511) array.
// int4-vectorized loads: thread reads 4x int4 (64B contiguous).
__global__ __launch_bounds__(256) void partition(const int* __restrict__ src,
                                                 const int* __restrict__ dst,
                                                 int* __restrict__ bcur,
                                                 int* __restrict__ pair, int e, int nb) {
    __shared__ int lh[256], cb[256];
    int t = threadIdx.x;
    int base = blockIdx.x * P3TILE;
    lh[t] = 0;
    __syncthreads();
    int s[16], d[16], r[16];
    if (base + P3TILE <= e) {
        const int4* s4 = (const int4*)(src + base);
        const int4* d4 = (const int4*)(dst + base);
#pragma unroll
        for (int k = 0; k < 4; ++k) {
            int4 sv = s4[t * 4 + k];
            int4 dv = d4[t * 4 + k];
            s[k * 4 + 0] = sv.x; s[k * 4 + 1] = sv.y;
            s[k * 4 + 2] = sv.z; s[k * 4 + 3] = sv.w;
            d[k * 4 + 0] = dv.x; d[k * 4 + 1] = dv.y;
            d[k * 4 + 2] = dv.z; d[k * 4 + 3] = dv.w;
        }
#pragma unroll
        for (int k = 0; k < 16; ++k)
            r[k] = atomicAdd(&lh[d[k] >> BSHIFT], 1);
        __syncthreads();
        if (t < nb && lh[t]) cb[t] = atomicAdd(&bcur[t], lh[t]);
        __syncthreads();
#pragma unroll
        for (int k = 0; k < 16; ++k)
            pair[cb[d[k] >> BSHIFT] + r[k]] = (s[k] << BSHIFT) | (d[k] & (NPB - 1));
    } else {
#pragma unroll
        for (int k = 0; k < 16; ++k) {
            int i = base + t * 16 + k;
            if (i < e) {
                s[k] = src[i];
                d[k] = dst[i];
                r[k] = atomicAdd(&lh[d[k] >> BSHIFT], 1);
            }
        }
        __syncthreads();
        if (t < nb && lh[t]) cb[t] = atomicAdd(&bcur[t], lh[t]);
        __syncthreads();
#pragma unroll
        for (int k = 0; k < 16; ++k) {
            int i = base + t * 16 + k;
            if (i < e)
                pair[cb[d[k] >> BSHIFT] + r[k]] = (s[k] << BSHIFT) | (d[k] & (NPB - 1));
        }
    }
}

// 1024 threads/block: 16 waves for latency hiding
__global__ __launch_bounds__(1024) void build_csr(const int* __restrict__ pair,
                                                  const int* __restrict__ bbase,
                                                  int* __restrict__ offsets,
                                                  float* __restrict__ invdeg,
                                                  int* __restrict__ col, int n) {
    __shared__ int bins[NPB], cur[NPB], sd[NPB];
    int b = blockIdx.x, t = threadIdx.x;
    int cbase = bbase[b], cend = bbase[b + 1];
    int v0 = b << BSHIFT;
    if (t < NPB) bins[t] = 0;
    __syncthreads();
    for (int i = cbase + t; i < cend; i += 1024)
        atomicAdd(&bins[pair[i] & (NPB - 1)], 1);
    __syncthreads();
    int d = (t < NPB) ? bins[t] : 0;
    if (t < NPB) sd[t] = d;
    __syncthreads();
    for (int off = 1; off < NPB; off <<= 1) {
        int u = (t < NPB && t >= off) ? sd[t - off] : 0;
        __syncthreads();
        if (t < NPB) sd[t] += u;
        __syncthreads();
    }
    if (t < NPB) {
        int excl = sd[t] - d;
        cur[t] = excl;
        int v = v0 + t;
        if (v < n) {
            offsets[v] = cbase + excl;
            invdeg[v] = d > 0 ? 1.0f / (float)d : 0.0f;
        }
    }
    __syncthreads();
    for (int i = cbase + t; i < cend; i += 1024) {
        int p = pair[i];
        int pos = atomicAdd(&cur[p & (NPB - 1)], 1);
        col[cbase + pos] = p >> BSHIFT;
    }
}

// ---------------- weight prep ----------------

__global__ __launch_bounds__(256) void prep_w(const float* __restrict__ Ws,
                                              const float* __restrict__ Wn,
                                              ushort* __restrict__ Wcat, int total) {
    int i = blockIdx.x * 256 + threadIdx.x;
    if (i >= total) return;
    int l = i >> 13;
    int r = i & 8191;
    int j = r >> 7;
    int k = r & 127;
    float v = (k < 64) ? Ws[l * 4096 + j * 64 + k] : Wn[l * 4096 + j * 64 + (k - 64)];
    Wcat[i] = f2b(v);
}

// ---------------- neighbor mean: quarter-wave/node, fp8 gather (64B rows) ----
// 32-edge windows: all 8 uint4 gathers issued before any accf8 consumption,
// doubling per-wave loads-in-flight (the kernel is latency-bound).

__global__ __launch_bounds__(256) void aggregate_fp8(const uchar* __restrict__ h8,
                                                     ushort* __restrict__ nmb,
                                                     const int* __restrict__ offsets,
                                                     const int* __restrict__ col,
                                                     const float* __restrict__ invdeg,
                                                     int n) {
    int t = threadIdx.x, lane = t & 63, wid = t >> 6;
    int q = lane >> 4;          // quarter -> node
    int fl = lane & 15;         // col staging lane
    int e4 = lane & 3;          // which 16B (16 features) of the 64B row
    int sl = (lane >> 2) & 3;   // edge slot
    int nwaves = gridDim.x * 4;
    int ngrp = (n + 3) >> 2;
    for (int w = blockIdx.x * 4 + wid; w < ngrp; w += nwaves) {
        int v = w * 4 + q;
        bool valid = v < n;
        int vv = valid ? v : n - 1;
        int o0 = offsets[vv], o1 = offsets[vv + 1];
        int deg = o1 - o0;
        const int* cp = col + o0;
        int deg32 = deg & ~31;
        int deg16 = deg & ~15;
        float acc[16];
#pragma unroll
        for (int k = 0; k < 16; ++k) acc[k] = 0.f;
        // main: 32-edge windows, col indices prefetched one window ahead
        int ilo = 0, ihi = 0;
        if (deg32 > 0) { ilo = cp[fl]; ihi = cp[16 + fl]; }
        for (int base = 0; base < deg32; base += 32) {
            int clo = ilo, chi = ihi;
            if (base + 32 < deg32) {
                ilo = cp[base + 32 + fl];
                ihi = cp[base + 48 + fl];
            }
            int ne[8];
#pragma unroll
            for (int jj = 0; jj < 4; ++jj)
                ne[jj] = __shfl(clo, q * 16 + jj * 4 + sl);
#pragma unroll
            for (int jj = 0; jj < 4; ++jj)
                ne[4 + jj] = __shfl(chi, q * 16 + jj * 4 + sl);
            uint4 hv[8];
#pragma unroll
            for (int jj = 0; jj < 8; ++jj)
                hv[jj] = *(const uint4*)&h8[(size_t)ne[jj] * HID + e4 * 16];
#pragma unroll
            for (int jj = 0; jj < 8; ++jj) accf8(acc, hv[jj]);
        }
        // 16-edge remainder chunk
        if (deg16 > deg32) {
            int ci = cp[deg32 + fl];
#pragma unroll
            for (int jj = 0; jj < 16; jj += 4) {
                int ne2 = __shfl(ci, q * 16 + jj + sl);
                uint4 hv2 = *(const uint4*)&h8[(size_t)ne2 * HID + e4 * 16];
                accf8(acc, hv2);
            }
        }
        // tail (<16 edges): guarded, no shfl (direct quarter-local col loads)
        for (int jj = 0; jj < 16; jj += 4) {
            if (deg16 + jj >= deg) break;   // uniform within quarter
            int j = deg16 + jj + sl;
            if (j < deg) {
                int ne2 = cp[j];
                uint4 hv2 = *(const uint4*)&h8[(size_t)ne2 * HID + e4 * 16];
                accf8(acc, hv2);
            }
        }
        // reduce over the 4 edge slots (lane bits 2-3)
#pragma unroll
        for (int k = 0; k < 16; ++k) {
            acc[k] += __shfl_xor(acc[k], 4);
            acc[k] += __shfl_xor(acc[k], 8);
        }
        if (valid && sl == 0) {
            float s = invdeg[vv];
            uint4 lo, hi;
            lo.x = (uint)f2b(acc[0] * s) | ((uint)f2b(acc[1] * s) << 16);
            lo.y = (uint)f2b(acc[2] * s) | ((uint)f2b(acc[3] * s) << 16);
            lo.z = (uint)f2b(acc[4] * s) | ((uint)f2b(acc[5] * s) << 16);
            lo.w = (uint)f2b(acc[6] * s) | ((uint)f2b(acc[7] * s) << 16);
            hi.x = (uint)f2b(acc[8] * s) | ((uint)f2b(acc[9] * s) << 16);
            hi.y = (uint)f2b(acc[10] * s) | ((uint)f2b(acc[11] * s) << 16);
            hi.z = (uint)f2b(acc[12] * s) | ((uint)f2b(acc[13] * s) << 16);
            hi.w = (uint)f2b(acc[14] * s) | ((uint)f2b(acc[15] * s) << 16);
            *(uint4*)&nmb[(size_t)v * HID + e4 * 16] = lo;
            *(uint4*)&nmb[(size_t)v * HID + e4 * 16 + 8] = hi;
        }
    }
}

// ---------------- per-layer transform via MFMA, bf16 residual ----------------

__global__ __launch_bounds__(256) void transform_mfma(
    const ushort* __restrict__ hbm, const ushort* __restrict__ nmb,
    ushort* __restrict__ hbout, uchar* __restrict__ h8out,
    float* __restrict__ outF, const ushort* __restrict__ Wcat,
    const float* __restrict__ bias, const float* __restrict__ gamma,
    const float* __restrict__ beta, int n, int last) {
    int t = threadIdx.x, lane = t & 63, wid = t >> 6;
    int c = lane & 15, g = lane >> 4;
    bf16x8 Bf[4][4];
#pragma unroll
    for (int tt = 0; tt < 4; ++tt)
#pragma unroll
        for (int s = 0; s < 4; ++s)
            Bf[s][tt] = *(const bf16x8*)&Wcat[(tt * 16 + c) * 128 + s * 32 + g * 8];
    float bcol[4], gcol[4], btc[4];
#pragma unroll
    for (int tt = 0; tt < 4; ++tt) {
        bcol[tt] = bias[tt * 16 + c];
        gcol[tt] = gamma[tt * 16 + c];
        btc[tt] = beta[tt * 16 + c];
    }
    int ntiles = (n + 15) >> 4;
    int nw = gridDim.x * 4;
    for (int tile = blockIdx.x * 4 + wid; tile < ntiles; tile += nw) {
        int m0 = tile << 4;
        int node = m0 + c;
        int nodeL = node < n ? node : n - 1;
        bf16x8 Af[4];
#pragma unroll
        for (int s = 0; s < 2; ++s)
            Af[s] = *(const bf16x8*)&hbm[(size_t)nodeL * HID + s * 32 + g * 8];
#pragma unroll
        for (int s = 0; s < 2; ++s)
            Af[2 + s] = *(const bf16x8*)&nmb[(size_t)nodeL * HID + s * 32 + g * 8];
        f32x4 acc[4] = {{0, 0, 0, 0}, {0, 0, 0, 0}, {0, 0, 0, 0}, {0, 0, 0, 0}};
#pragma unroll
        for (int tt = 0; tt < 4; ++tt)
#pragma unroll
            for (int s = 0; s < 4; ++s)
                acc[tt] = __builtin_amdgcn_mfma_f32_16x16x32_bf16(Af[s], Bf[s][tt],
                                                                 acc[tt], 0, 0, 0);
        float v[4][4];
#pragma unroll
        for (int tt = 0; tt < 4; ++tt)
#pragma unroll
            for (int r = 0; r < 4; ++r) v[tt][r] = acc[tt][r] + bcol[tt];
#pragma unroll
        for (int r = 0; r < 4; ++r) {
            float s = v[0][r] + v[1][r] + v[2][r] + v[3][r];
            s += __shfl_xor(s, 1);
            s += __shfl_xor(s, 2);
            s += __shfl_xor(s, 4);
            s += __shfl_xor(s, 8);
            float mu = s * (1.0f / 64.0f);
            float ss = 0.f;
#pragma unroll
            for (int tt = 0; tt < 4; ++tt) {
                float d = v[tt][r] - mu;
                ss += d * d;
            }
            ss += __shfl_xor(ss, 1);
            ss += __shfl_xor(ss, 2);
            ss += __shfl_xor(ss, 4);
            ss += __shfl_xor(ss, 8);
            float inv = rsqrtf(ss * (1.0f / 64.0f) + 1e-5f);
            int nr = m0 + g * 4 + r;
            if (nr < n) {
#pragma unroll
                for (int tt = 0; tt < 4; ++tt) {
                    int j = tt * 16 + c;
                    float hl = (v[tt][r] - mu) * inv * gcol[tt] + btc[tt];
                    float hv = b2f(hbm[(size_t)nr * HID + j]);
                    float o = hv + fmaxf(hl, 0.0f);
                    if (last) {
                        outF[(size_t)nr * HID + j] = o;   // hb/h8 writes dead
                    } else {
                        hbout[(size_t)nr * HID + j] = f2b(o);
                        h8out[(size_t)nr * HID + j] = f2fp8(o);
                    }
                }
            }
        }
    }
}

// ---------------- launcher ----------------

extern "C" void kernel_launch(void* const* d_in, const int* in_sizes, int n_in,
                              void* d_out, int out_size, void* d_ws, size_t ws_size,
                              hipStream_t stream) {
    const float* x = (const float*)d_in[0];
    const int* edge_src = (const int*)d_in[1];
    const int* edge_dst = (const int*)d_in[2];
    const float* W_in = (const float*)d_in[3];
    const float* b_in = (const float*)d_in[4];
    const float* Ws_self = (const float*)d_in[5];
    const float* Ws_neigh = (const float*)d_in[6];
    const float* biases = (const float*)d_in[7];
    const float* gammas = (const float*)d_in[8];
    const float* betas = (const float*)d_in[9];
    float* out = (float*)d_out;

    int n = in_sizes[0] / 8;
    int e = in_sizes[1];
    int nb = (n + NPB - 1) >> BSHIFT;

    char* w = (char*)d_ws;
    size_t off = 0;
    auto carve = [&](size_t bytes) -> void* {
        void* p = w + off;
        off = (off + bytes + 255) & ~(size_t)255;
        return p;
    };
    int* offsets = (int*)carve((size_t)(n + 1) * 4);
    float* invdeg = (float*)carve((size_t)n * 4);
    int* bcnt = (int*)carve(1024 * 4);
    int* bbase = (int*)carve(1024 * 4);
    int* bcur = (int*)carve(1024 * 4);
    int* col = (int*)carve((size_t)e * 4);
    int* pairbuf = (int*)carve((size_t)e * 4);
    ushort* hb = (ushort*)carve((size_t)n * HID * 2);
    ushort* nm16 = (ushort*)carve((size_t)n * HID * 2);
    uchar* h8 = (uchar*)carve((size_t)n * HID);
    ushort* Wcat = (ushort*)carve(3 * 64 * 128 * 2);
    (void)ws_size;

    hipMemsetAsync(bcnt, 0, 1024 * 4, stream);
    hist_input<<<HISTB + 2048, 256, 0, stream>>>(edge_dst, bcnt, e, nb,
                                                 x, W_in, b_in, hb, h8, n, 2048);
    bucket_scan<<<1, 256, 0, stream>>>(bcnt, bbase, bcur, offsets, e, nb, n);
    partition<<<(e + P3TILE - 1) / P3TILE, 256, 0, stream>>>(edge_src, edge_dst, bcur,
                                                            pairbuf, e, nb);
    build_csr<<<nb, 1024, 0, stream>>>(pairbuf, bbase, offsets, invdeg, col, n);
    prep_w<<<(3 * 8192 + 255) / 256, 256, 0, stream>>>(Ws_self, Ws_neigh, Wcat, 3 * 8192);

    // grid sized so every wave runs <=3 node-groups (avoids the 4th-group tail)
    int ngrp = (n + 3) >> 2;
    int agblocks = (ngrp + 11) / 12;           // ceil(ngrp / (3 groups * 4 waves))
    int tfblocks = ((n + 15) / 16 + 3) / 4;
    for (int l = 0; l < 3; ++l) {
        aggregate_fp8<<<agblocks, 256, 0, stream>>>(h8, nm16, offsets, col, invdeg, n);
        transform_mfma<<<tfblocks, 256, 0, stream>>>(hb, nm16, hb, h8, out,
                                                     Wcat + (size_t)l * 8192,
                                                     biases + l * 64, gammas + l * 64,
                                                     betas + l * 64, n, l == 2 ? 1 : 0);
    }
}

// Round 3
// 303.732 us; speedup vs baseline: 1.2289x; 1.1201x over previous
//
#include <hip/hip_runtime.h>

#define HID 64
#define BSHIFT 9            // 512 nodes per bucket
#define NPB 512
#define P3TILE 4096         // edges per block-tile in partition
#define HISTB 512           // hist blocks in fused hist+input kernel
#define PREPB 96            // prep_w blocks fused into hist_input

typedef unsigned int uint;
typedef unsigned short ushort;
typedef unsigned char uchar;
typedef float f32x2 __attribute__((ext_vector_type(2)));
typedef float f32x4 __attribute__((ext_vector_type(4)));
typedef short bf16x8 __attribute__((ext_vector_type(8)));

__device__ inline ushort f2b(float f) {  // fp32 -> bf16 RNE
    uint u = __float_as_uint(f);
    return (ushort)((u + 0x7fffu + ((u >> 16) & 1u)) >> 16);
}

__device__ inline float b2f(ushort b) { return __uint_as_float((uint)b << 16); }

// unpack 16 fp8-e4m3 (uint4) and accumulate into a[8] float2 pairs.
// cvt_pk_f32_fp8 produces f32 PAIRS; accumulating as 2-wide vectors lets the
// backend select v_pk_add_f32 (VOP3P): 16 instrs/uint4 instead of 24.
__device__ inline void accf8(f32x2* a, uint4 hv) {
    a[0] += __builtin_bit_cast(f32x2, __builtin_amdgcn_cvt_pk_f32_fp8(hv.x, false));
    a[1] += __builtin_bit_cast(f32x2, __builtin_amdgcn_cvt_pk_f32_fp8(hv.x, true));
    a[2] += __builtin_bit_cast(f32x2, __builtin_amdgcn_cvt_pk_f32_fp8(hv.y, false));
    a[3] += __builtin_bit_cast(f32x2, __builtin_amdgcn_cvt_pk_f32_fp8(hv.y, true));
    a[4] += __builtin_bit_cast(f32x2, __builtin_amdgcn_cvt_pk_f32_fp8(hv.z, false));
    a[5] += __builtin_bit_cast(f32x2, __builtin_amdgcn_cvt_pk_f32_fp8(hv.z, true));
    a[6] += __builtin_bit_cast(f32x2, __builtin_amdgcn_cvt_pk_f32_fp8(hv.w, false));
    a[7] += __builtin_bit_cast(f32x2, __builtin_amdgcn_cvt_pk_f32_fp8(hv.w, true));
}

__device__ inline uchar f2fp8(float f) {
    return (uchar)(__builtin_amdgcn_cvt_pk_fp8_f32(f, f, 0, false) & 0xff);
}

// ------- fused: bucket histogram + input transform + weight prep -------
// blocks [0, HISTB): histogram of dst into buckets
// blocks [HISTB, HISTB+inb): h0 = relu(x @ W_in^T + b_in) -> bf16 hb + fp8 h8
// blocks [HISTB+inb, HISTB+inb+PREPB): Wcat = bf16 concat of Ws_self|Ws_neigh

__global__ __launch_bounds__(256) void hist_input(const int* __restrict__ dst,
                                                  int* __restrict__ bcnt, int e, int nb,
                                                  const float* __restrict__ x,
                                                  const float* __restrict__ W_in,
                                                  const float* __restrict__ b_in,
                                                  ushort* __restrict__ hb,
                                                  uchar* __restrict__ h8, int n,
                                                  int inb,
                                                  const float* __restrict__ Ws,
                                                  const float* __restrict__ Wn,
                                                  ushort* __restrict__ Wcat) {
    __shared__ float smem[576];
    int t = threadIdx.x;
    int b = blockIdx.x;
    if (b < HISTB) {
        int* lh = (int*)smem;
        lh[t] = 0;
        __syncthreads();
        for (int i = b * 256 + t; i < e; i += HISTB * 256)
            atomicAdd(&lh[dst[i] >> BSHIFT], 1);
        __syncthreads();
        if (t < nb && lh[t]) atomicAdd(&bcnt[t], lh[t]);
        return;
    }
    if (b >= HISTB + inb) {   // weight prep range
        int i = (b - HISTB - inb) * 256 + t;
        if (i < 3 * 8192) {
            int l = i >> 13;
            int r = i & 8191;
            int j = r >> 7;
            int k = r & 127;
            float v = (k < 64) ? Ws[l * 4096 + j * 64 + k]
                               : Wn[l * 4096 + j * 64 + (k - 64)];
            Wcat[i] = f2b(v);
        }
        return;
    }
    int ib = b - HISTB;
    float* WlT = smem;          // [8][64]
    float* bl = smem + 512;     // [64]
    for (int i = t; i < 512; i += 256) {
        int j = i >> 3, k = i & 7;
        WlT[k * 64 + j] = W_in[i];
    }
    if (t < 64) bl[t] = b_in[t];
    __syncthreads();
    int total2 = n * 32;
    for (int i = ib * 256 + t; i < total2; i += inb * 256) {
        int v = i >> 5;
        int jp = i & 31;
        int j0 = jp * 2, j1 = jp * 2 + 1;
        const float* xr = x + (size_t)v * 8;
        float s0 = bl[j0], s1 = bl[j1];
#pragma unroll
        for (int k = 0; k < 8; ++k) {
            float xv = xr[k];
            s0 += xv * WlT[k * 64 + j0];
            s1 += xv * WlT[k * 64 + j1];
        }
        float o0 = fmaxf(s0, 0.0f), o1 = fmaxf(s1, 0.0f);
        ((uint*)hb)[i] = (uint)f2b(o0) | ((uint)f2b(o1) << 16);
        int pk = __builtin_amdgcn_cvt_pk_fp8_f32(o0, o1, 0, false);
        *(ushort*)&h8[(size_t)2 * i] = (ushort)(pk & 0xffff);
    }
}

__global__ void bucket_scan(const int* __restrict__ bcnt, int* __restrict__ bbase,
                            int* __restrict__ bcur, int* __restrict__ offsets,
                            int e, int nb, int n) {
    __shared__ int sd[256];
    int t = threadIdx.x;
    int v = (t < nb) ? bcnt[t] : 0;
    sd[t] = v;
    __syncthreads();
    for (int off = 1; off < 256; off <<= 1) {
        int u = (t >= off) ? sd[t - off] : 0;
        __syncthreads();
        sd[t] += u;
        __syncthreads();
    }
    int excl = t ? sd[t - 1] : 0;
    if (t < nb) { bbase[t] = excl; bcur[t] = excl; }
    if (t == nb) bbase[t] = e;
    if (t == 0) offsets[n] = e;
}

// partition edges into bucket-contiguous packed (src<<9 | dst&511) array.
// int4-vectorized loads: thread reads 4x int4 (64B contiguous).
__global__ __launch_bounds__(256) void partition(const int* __restrict__ src,
                                                 const int* __restrict__ dst,
                                                 int* __restrict__ bcur,
                                                 int* __restrict__ pair, int e, int nb) {
    __shared__ int lh[256], cb[256];
    int t = threadIdx.x;
    int base = blockIdx.x * P3TILE;
    lh[t] = 0;
    __syncthreads();
    int s[16], d[16], r[16];
    if (base + P3TILE <= e) {
        const int4* s4 = (const int4*)(src + base);
        const int4* d4 = (const int4*)(dst + base);
#pragma unroll
        for (int k = 0; k < 4; ++k) {
            int4 sv = s4[t * 4 + k];
            int4 dv = d4[t * 4 + k];
            s[k * 4 + 0] = sv.x; s[k * 4 + 1] = sv.y;
            s[k * 4 + 2] = sv.z; s[k * 4 + 3] = sv.w;
            d[k * 4 + 0] = dv.x; d[k * 4 + 1] = dv.y;
            d[k * 4 + 2] = dv.z; d[k * 4 + 3] = dv.w;
        }
#pragma unroll
        for (int k = 0; k < 16; ++k)
            r[k] = atomicAdd(&lh[d[k] >> BSHIFT], 1);
        __syncthreads();
        if (t < nb && lh[t]) cb[t] = atomicAdd(&bcur[t], lh[t]);
        __syncthreads();
#pragma unroll
        for (int k = 0; k < 16; ++k)
            pair[cb[d[k] >> BSHIFT] + r[k]] = (s[k] << BSHIFT) | (d[k] & (NPB - 1));
    } else {
#pragma unroll
        for (int k = 0; k < 16; ++k) {
            int i = base + t * 16 + k;
            if (i < e) {
                s[k] = src[i];
                d[k] = dst[i];
                r[k] = atomicAdd(&lh[d[k] >> BSHIFT], 1);
            }
        }
        __syncthreads();
        if (t < nb && lh[t]) cb[t] = atomicAdd(&bcur[t], lh[t]);
        __syncthreads();
#pragma unroll
        for (int k = 0; k < 16; ++k) {
            int i = base + t * 16 + k;
            if (i < e)
                pair[cb[d[k] >> BSHIFT] + r[k]] = (s[k] << BSHIFT) | (d[k] & (NPB - 1));
        }
    }
}

// 1024 threads/block: 16 waves for latency hiding
__global__ __launch_bounds__(1024) void build_csr(const int* __restrict__ pair,
                                                  const int* __restrict__ bbase,
                                                  int* __restrict__ offsets,
                                                  float* __restrict__ invdeg,
                                                  int* __restrict__ col, int n) {
    __shared__ int bins[NPB], cur[NPB], sd[NPB];
    int b = blockIdx.x, t = threadIdx.x;
    int cbase = bbase[b], cend = bbase[b + 1];
    int v0 = b << BSHIFT;
    if (t < NPB) bins[t] = 0;
    __syncthreads();
    for (int i = cbase + t; i < cend; i += 1024)
        atomicAdd(&bins[pair[i] & (NPB - 1)], 1);
    __syncthreads();
    int d = (t < NPB) ? bins[t] : 0;
    if (t < NPB) sd[t] = d;
    __syncthreads();
    for (int off = 1; off < NPB; off <<= 1) {
        int u = (t < NPB && t >= off) ? sd[t - off] : 0;
        __syncthreads();
        if (t < NPB) sd[t] += u;
        __syncthreads();
    }
    if (t < NPB) {
        int excl = sd[t] - d;
        cur[t] = excl;
        int v = v0 + t;
        if (v < n) {
            offsets[v] = cbase + excl;
            invdeg[v] = d > 0 ? 1.0f / (float)d : 0.0f;
        }
    }
    __syncthreads();
    for (int i = cbase + t; i < cend; i += 1024) {
        int p = pair[i];
        int pos = atomicAdd(&cur[p & (NPB - 1)], 1);
        col[cbase + pos] = p >> BSHIFT;
    }
}

// ---------------- neighbor mean: quarter-wave/node, fp8 gather (64B rows) ----

__global__ __launch_bounds__(256) void aggregate_fp8(const uchar* __restrict__ h8,
                                                     ushort* __restrict__ nmb,
                                                     const int* __restrict__ offsets,
                                                     const int* __restrict__ col,
                                                     const float* __restrict__ invdeg,
                                                     int n) {
    int t = threadIdx.x, lane = t & 63, wid = t >> 6;
    int q = lane >> 4;          // quarter -> node
    int fl = lane & 15;         // col staging lane
    int e4 = lane & 3;          // which 16B (16 features) of the 64B row
    int sl = (lane >> 2) & 3;   // edge slot
    int nwaves = gridDim.x * 4;
    int ngrp = (n + 3) >> 2;
    for (int w = blockIdx.x * 4 + wid; w < ngrp; w += nwaves) {
        int v = w * 4 + q;
        bool valid = v < n;
        int vv = valid ? v : n - 1;
        int o0 = offsets[vv], o1 = offsets[vv + 1];
        int deg = o1 - o0;
        const int* cp = col + o0;
        int deg16 = deg & ~15;
        f32x2 acc2[8];
        float* af = (float*)acc2;
#pragma unroll
        for (int k = 0; k < 8; ++k) acc2[k] = f32x2{0.f, 0.f};
        for (int base = 0; base < deg16; base += 16) {
            int idx16 = cp[base + fl];  // full chunk: unguarded, coalesced
#pragma unroll
            for (int jj = 0; jj < 16; jj += 4) {
                int ne = __shfl(idx16, q * 16 + jj + sl);
                uint4 hv = *(const uint4*)&h8[(size_t)ne * HID + e4 * 16];
                accf8(acc2, hv);
            }
        }
        // tail (<16 edges): guarded, no shfl (direct quarter-local col loads)
        for (int jj = 0; jj < 16; jj += 4) {
            if (deg16 + jj >= deg) break;   // uniform within quarter
            int j = deg16 + jj + sl;
            if (j < deg) {
                int ne = cp[j];
                uint4 hv = *(const uint4*)&h8[(size_t)ne * HID + e4 * 16];
                accf8(acc2, hv);
            }
        }
        // reduce over the 4 edge slots (lane bits 2-3)
#pragma unroll
        for (int k = 0; k < 16; ++k) {
            af[k] += __shfl_xor(af[k], 4);
            af[k] += __shfl_xor(af[k], 8);
        }
        if (valid && sl == 0) {
            float s = invdeg[vv];
            uint4 lo, hi;
            lo.x = (uint)f2b(af[0] * s) | ((uint)f2b(af[1] * s) << 16);
            lo.y = (uint)f2b(af[2] * s) | ((uint)f2b(af[3] * s) << 16);
            lo.z = (uint)f2b(af[4] * s) | ((uint)f2b(af[5] * s) << 16);
            lo.w = (uint)f2b(af[6] * s) | ((uint)f2b(af[7] * s) << 16);
            hi.x = (uint)f2b(af[8] * s) | ((uint)f2b(af[9] * s) << 16);
            hi.y = (uint)f2b(af[10] * s) | ((uint)f2b(af[11] * s) << 16);
            hi.z = (uint)f2b(af[12] * s) | ((uint)f2b(af[13] * s) << 16);
            hi.w = (uint)f2b(af[14] * s) | ((uint)f2b(af[15] * s) << 16);
            *(uint4*)&nmb[(size_t)v * HID + e4 * 16] = lo;
            *(uint4*)&nmb[(size_t)v * HID + e4 * 16 + 8] = hi;
        }
    }
}

// ---------------- per-layer transform via MFMA, bf16 residual ----------------

__global__ __launch_bounds__(256) void transform_mfma(
    const ushort* __restrict__ hbm, const ushort* __restrict__ nmb,
    ushort* __restrict__ hbout, uchar* __restrict__ h8out,
    float* __restrict__ outF, const ushort* __restrict__ Wcat,
    const float* __restrict__ bias, const float* __restrict__ gamma,
    const float* __restrict__ beta, int n, int last) {
    int t = threadIdx.x, lane = t & 63, wid = t >> 6;
    int c = lane & 15, g = lane >> 4;
    bf16x8 Bf[4][4];
#pragma unroll
    for (int tt = 0; tt < 4; ++tt)
#pragma unroll
        for (int s = 0; s < 4; ++s)
            Bf[s][tt] = *(const bf16x8*)&Wcat[(tt * 16 + c) * 128 + s * 32 + g * 8];
    float bcol[4], gcol[4], btc[4];
#pragma unroll
    for (int tt = 0; tt < 4; ++tt) {
        bcol[tt] = bias[tt * 16 + c];
        gcol[tt] = gamma[tt * 16 + c];
        btc[tt] = beta[tt * 16 + c];
    }
    int ntiles = (n + 15) >> 4;
    int nw = gridDim.x * 4;
    for (int tile = blockIdx.x * 4 + wid; tile < ntiles; tile += nw) {
        int m0 = tile << 4;
        int node = m0 + c;
        int nodeL = node < n ? node : n - 1;
        bf16x8 Af[4];
#pragma unroll
        for (int s = 0; s < 2; ++s)
            Af[s] = *(const bf16x8*)&hbm[(size_t)nodeL * HID + s * 32 + g * 8];
#pragma unroll
        for (int s = 0; s < 2; ++s)
            Af[2 + s] = *(const bf16x8*)&nmb[(size_t)nodeL * HID + s * 32 + g * 8];
        f32x4 acc[4] = {{0, 0, 0, 0}, {0, 0, 0, 0}, {0, 0, 0, 0}, {0, 0, 0, 0}};
#pragma unroll
        for (int tt = 0; tt < 4; ++tt)
#pragma unroll
            for (int s = 0; s < 4; ++s)
                acc[tt] = __builtin_amdgcn_mfma_f32_16x16x32_bf16(Af[s], Bf[s][tt],
                                                                 acc[tt], 0, 0, 0);
        float v[4][4];
#pragma unroll
        for (int tt = 0; tt < 4; ++tt)
#pragma unroll
            for (int r = 0; r < 4; ++r) v[tt][r] = acc[tt][r] + bcol[tt];
#pragma unroll
        for (int r = 0; r < 4; ++r) {
            float s = v[0][r] + v[1][r] + v[2][r] + v[3][r];
            s += __shfl_xor(s, 1);
            s += __shfl_xor(s, 2);
            s += __shfl_xor(s, 4);
            s += __shfl_xor(s, 8);
            float mu = s * (1.0f / 64.0f);
            float ss = 0.f;
#pragma unroll
            for (int tt = 0; tt < 4; ++tt) {
                float d = v[tt][r] - mu;
                ss += d * d;
            }
            ss += __shfl_xor(ss, 1);
            ss += __shfl_xor(ss, 2);
            ss += __shfl_xor(ss, 4);
            ss += __shfl_xor(ss, 8);
            float inv = rsqrtf(ss * (1.0f / 64.0f) + 1e-5f);
            int nr = m0 + g * 4 + r;
            if (nr < n) {
#pragma unroll
                for (int tt = 0; tt < 4; ++tt) {
                    int j = tt * 16 + c;
                    float hl = (v[tt][r] - mu) * inv * gcol[tt] + btc[tt];
                    float hv = b2f(hbm[(size_t)nr * HID + j]);
                    float o = hv + fmaxf(hl, 0.0f);
                    if (last) {
                        outF[(size_t)nr * HID + j] = o;   // hb/h8 writes dead
                    } else {
                        hbout[(size_t)nr * HID + j] = f2b(o);
                        h8out[(size_t)nr * HID + j] = f2fp8(o);
                    }
                }
            }
        }
    }
}

// ---------------- launcher ----------------

extern "C" void kernel_launch(void* const* d_in, const int* in_sizes, int n_in,
                              void* d_out, int out_size, void* d_ws, size_t ws_size,
                              hipStream_t stream) {
    const float* x = (const float*)d_in[0];
    const int* edge_src = (const int*)d_in[1];
    const int* edge_dst = (const int*)d_in[2];
    const float* W_in = (const float*)d_in[3];
    const float* b_in = (const float*)d_in[4];
    const float* Ws_self = (const float*)d_in[5];
    const float* Ws_neigh = (const float*)d_in[6];
    const float* biases = (const float*)d_in[7];
    const float* gammas = (const float*)d_in[8];
    const float* betas = (const float*)d_in[9];
    float* out = (float*)d_out;

    int n = in_sizes[0] / 8;
    int e = in_sizes[1];
    int nb = (n + NPB - 1) >> BSHIFT;

    char* w = (char*)d_ws;
    size_t off = 0;
    auto carve = [&](size_t bytes) -> void* {
        void* p = w + off;
        off = (off + bytes + 255) & ~(size_t)255;
        return p;
    };
    int* offsets = (int*)carve((size_t)(n + 1) * 4);
    float* invdeg = (float*)carve((size_t)n * 4);
    int* bcnt = (int*)carve(1024 * 4);
    int* bbase = (int*)carve(1024 * 4);
    int* bcur = (int*)carve(1024 * 4);
    int* col = (int*)carve((size_t)e * 4);
    int* pairbuf = (int*)carve((size_t)e * 4);
    ushort* hb = (ushort*)carve((size_t)n * HID * 2);
    ushort* nm16 = (ushort*)carve((size_t)n * HID * 2);
    uchar* h8 = (uchar*)carve((size_t)n * HID);
    ushort* Wcat = (ushort*)carve(3 * 64 * 128 * 2);
    (void)ws_size;

    hipMemsetAsync(bcnt, 0, 1024 * 4, stream);
    hist_input<<<HISTB + 2048 + PREPB, 256, 0, stream>>>(edge_dst, bcnt, e, nb,
                                                         x, W_in, b_in, hb, h8, n,
                                                         2048, Ws_self, Ws_neigh, Wcat);
    bucket_scan<<<1, 256, 0, stream>>>(bcnt, bbase, bcur, offsets, e, nb, n);
    partition<<<(e + P3TILE - 1) / P3TILE, 256, 0, stream>>>(edge_src, edge_dst, bcur,
                                                            pairbuf, e, nb);
    build_csr<<<nb, 1024, 0, stream>>>(pairbuf, bbase, offsets, invdeg, col, n);

    int tfblocks = ((n + 15) / 16 + 3) / 4;
    for (int l = 0; l < 3; ++l) {
        aggregate_fp8<<<2048, 256, 0, stream>>>(h8, nm16, offsets, col, invdeg, n);
        transform_mfma<<<tfblocks, 256, 0, stream>>>(hb, nm16, hb, h8, out,
                                                     Wcat + (size_t)l * 8192,
                                                     biases + l * 64, gammas + l * 64,
                                                     betas + l * 64, n, l == 2 ? 1 : 0);
    }
}